// Round 3
// baseline (354.571 us; speedup 1.0000x reference)
//
#include <hip/hip_runtime.h>
#include <stdint.h>

// Problem constants (from reference)
#define BOX 120
#define BOX2 (BOX * BOX)            // 14400
#define BOX3 (BOX * BOX * BOX)      // 1,728,000
#define NTYPES 11
#define NBATCH 4
#define BT (NBATCH * NTYPES)        // 44
#define MAXA 512
#define NNB 2
#define KCELLS 125

// Gather-path parameters
#define NBINS (BT * BOX2)           // 633,600 (bt, cellx, celly) bins
#define BINCAP 8                    // max atoms stored per bin (P(overflow)~1e-11 for uniform input)
#define YTILE 8                     // y-rows per gather block
#define NYT (BOX / YTILE)           // 15

#define WS_COUNTS_BYTES ((size_t)NBINS * 4)            // 2,534,400
#define WS_BINS_BYTES   ((size_t)NBINS * BINCAP * 2)   // 10,137,600
#define WS_NEEDED       (WS_COUNTS_BYTES + WS_BINS_BYTES)

// ---------------- gather path ----------------

// Zero the bin-count table (d_ws is poisoned 0xAA before every call).
__global__ __launch_bounds__(256)
void zero_counts_kernel(uint4* __restrict__ counts4, int n4) {
    int i = blockIdx.x * blockDim.x + threadIdx.x;
    if (i < n4) counts4[i] = make_uint4(0u, 0u, 0u, 0u);
}

// Bin atoms by (bt, cellx, celly). 22528 threads.
__global__ __launch_bounds__(256)
void bin_kernel(const float* __restrict__ coords,
                const int* __restrict__ num_atoms,
                uint32_t* __restrict__ counts,
                uint16_t* __restrict__ bins) {
    int tid = blockIdx.x * blockDim.x + threadIdx.x;
    if (tid >= BT * MAXA) return;
    int bt = tid / MAXA;
    int a  = tid % MAXA;
    if (a >= num_atoms[bt]) return;
    const float* p = coords + (size_t)bt * (3 * MAXA) + (size_t)a * 3;
    int cx = (int)floorf(p[0]);
    int cy = (int)floorf(p[1]);
    if ((unsigned)cx >= BOX || (unsigned)cy >= BOX) return; // margin=5 -> never taken
    int bin = (bt * BOX + cx) * BOX + cy;
    uint32_t idx = atomicAdd(&counts[bin], 1u);
    if (idx < BINCAP) bins[(size_t)bin * BINCAP + idx] = (uint16_t)a;
}

// One block per (bt, x, y-tile). Produces 8*120 voxels (write-only, no atomics,
// no pre-zero pass). Candidate atoms come from the 5x12 neighbouring (cx,cy)
// bins; truncation is cell-based (|voxel - floor(pos)| <= 2 per axis), matching
// the reference's neighbour-cell enumeration.
__global__ __launch_bounds__(256)
void gather_kernel(const float* __restrict__ coords,
                   const uint32_t* __restrict__ counts,
                   const uint16_t* __restrict__ bins,
                   float* __restrict__ out) {
    int b  = blockIdx.x;
    int bt = b / (BOX * NYT);
    int r  = b % (BOX * NYT);
    int x  = r / NYT;
    int y0 = (r % NYT) * YTILE;

    const int NB_Y = YTILE + 2 * NNB;          // 12 candidate cy rows
    __shared__ float4 s_at[5 * NB_Y * BINCAP]; // (py, pz, floor(py), floor(pz))
    __shared__ float  s_w[5 * NB_Y * BINCAP];  // exp(-(x-px)^2)
    __shared__ int    s_n;
    if (threadIdx.x == 0) s_n = 0;
    __syncthreads();

    int t = threadIdx.x;
    if (t < 5 * NB_Y) {
        int cxb = x - NNB + t / NB_Y;
        int cyb = y0 - NNB + t % NB_Y;
        if ((unsigned)cxb < BOX && (unsigned)cyb < BOX) {
            int bin = (bt * BOX + cxb) * BOX + cyb;
            int c = (int)counts[bin];
            if (c > BINCAP) c = BINCAP;
            if (c > 0) {
                int base = atomicAdd(&s_n, c);
                for (int k = 0; k < c; ++k) {
                    int a = bins[(size_t)bin * BINCAP + k];
                    const float* p = coords + (size_t)bt * (3 * MAXA) + (size_t)a * 3;
                    float px = p[0], py = p[1], pz = p[2];
                    float fx = (float)x - px;
                    s_at[base + k] = make_float4(py, pz, floorf(py), floorf(pz));
                    s_w[base + k]  = __expf(-fx * fx);
                }
            }
        }
    }
    __syncthreads();
    int n = s_n;

    size_t obase = (size_t)(bt * BOX + x) * BOX2 + (size_t)y0 * BOX;
    // 960 contiguous voxels per block, 256 threads, 4 strided iterations.
    for (int it = 0; it < 4; ++it) {
        int v = threadIdx.x + it * 256;
        if (v < YTILE * BOX) {
            float yf = (float)(y0 + v / BOX);
            float zf = (float)(v % BOX);
            float acc = 0.f;
            for (int i = 0; i < n; ++i) {
                float4 at = s_at[i];
                if (fabsf(yf - at.z) <= 2.0f && fabsf(zf - at.w) <= 2.0f) {
                    float dy = yf - at.x;
                    float dz = zf - at.y;
                    acc += s_w[i] * __expf(-(dy * dy + dz * dz));
                }
            }
            __builtin_nontemporal_store(acc, out + obase + v);
        }
    }
}

// ---------------- fallback path (zero + atomic scatter), used if ws too small ----------------

__global__ __launch_bounds__(256)
void zero_out_kernel(float4* __restrict__ out, int n4) {
    int i = blockIdx.x * blockDim.x + threadIdx.x;
    if (i < n4) out[i] = make_float4(0.f, 0.f, 0.f, 0.f);
}

__global__ __launch_bounds__(256)
void scatter_kernel(const float* __restrict__ coords,
                    const int* __restrict__ num_atoms,
                    float* __restrict__ out) {
    int idx = blockIdx.x * blockDim.x + threadIdx.x;
    const int total = BT * MAXA * KCELLS;
    if (idx >= total) return;
    int k   = idx % KCELLS;
    int tmp = idx / KCELLS;
    int a   = tmp % MAXA;
    int bt  = tmp / MAXA;
    if (a >= num_atoms[bt]) return;
    const float* p = coords + (size_t)bt * (3 * MAXA) + (size_t)a * 3;
    float px = p[0], py = p[1], pz = p[2];
    int dz = k % 5, t2 = k / 5;
    int dy = t2 % 5, dx = t2 / 5;
    int nx = (int)floorf(px) + dx - NNB;
    int ny = (int)floorf(py) + dy - NNB;
    int nz = (int)floorf(pz) + dz - NNB;
    if ((unsigned)nx >= BOX || (unsigned)ny >= BOX || (unsigned)nz >= BOX) return;
    float fx = (float)nx - px, fy = (float)ny - py, fz = (float)nz - pz;
    float val = __expf(-(fx * fx + fy * fy + fz * fz));
    atomicAdd(out + (size_t)bt * BOX3 + (size_t)((nx * BOX + ny) * BOX + nz), val);
}

extern "C" void kernel_launch(void* const* d_in, const int* in_sizes, int n_in,
                              void* d_out, int out_size, void* d_ws, size_t ws_size,
                              hipStream_t stream) {
    const float* coords    = (const float*)d_in[0];   // [4, 11, 1536] fp32
    const int*   num_atoms = (const int*)d_in[1];     // [4, 11] int32
    float*       out       = (float*)d_out;           // [4, 11, 120^3] fp32

    if (ws_size >= WS_NEEDED) {
        uint32_t* counts = (uint32_t*)d_ws;
        uint16_t* bins   = (uint16_t*)((char*)d_ws + WS_COUNTS_BYTES);

        int n4 = NBINS / 4;                           // 158,400 uint4s
        zero_counts_kernel<<<(n4 + 255) / 256, 256, 0, stream>>>((uint4*)counts, n4);

        bin_kernel<<<(BT * MAXA + 255) / 256, 256, 0, stream>>>(coords, num_atoms, counts, bins);

        int gblocks = BT * BOX * NYT;                 // 79,200
        gather_kernel<<<gblocks, 256, 0, stream>>>(coords, counts, bins, out);
    } else {
        int n4 = out_size / 4;
        zero_out_kernel<<<(n4 + 255) / 256, 256, 0, stream>>>((float4*)d_out, n4);
        const int total = BT * MAXA * KCELLS;
        scatter_kernel<<<(total + 255) / 256, 256, 0, stream>>>(coords, num_atoms, out);
    }
}

// Round 4
// 344.190 us; speedup vs baseline: 1.0302x; 1.0302x over previous
//
#include <hip/hip_runtime.h>
#include <stdint.h>

// Problem constants (from reference)
#define BOX 120
#define BOX2 (BOX * BOX)            // 14400
#define BOX3 (BOX * BOX * BOX)      // 1,728,000
#define NTYPES 11
#define NBATCH 4
#define BT (NBATCH * NTYPES)        // 44
#define MAXA 512
#define NNB 2

// Contribution cutoff: exp(-r2) < DELTA is dropped. r2 > 6.2 => ~48% of the
// 125 neighbour cells eliminated. Worst-case stacked error (<=4 overlapping
// atoms at this density) ~8e-3, vs 3.36e-2 harness threshold.
#define DELTA 2e-3f

// Exact-size vectorized zero of d_out: 2 float4 (32B) per thread.
// (hipMemsetAsync's fillBufferAligned writes 4x the buffer -> never use it.)
__global__ __launch_bounds__(256)
void zero_out_kernel(float4* __restrict__ out, int n4) {
    int i = (blockIdx.x * blockDim.x + threadIdx.x) * 2;
    if (i < n4)     out[i]     = make_float4(0.f, 0.f, 0.f, 0.f);
    if (i + 1 < n4) out[i + 1] = make_float4(0.f, 0.f, 0.f, 0.f);
}

// One thread per (bt, atom, dx, dy): 44*512*25 = 563,200 threads.
// Each thread handles one z-run of 5 contiguous voxels (L2-coalesced atomics).
// exp factoring: val = exp(-fx^2-fy^2) * exp(-fz^2); row-level and per-voxel
// cutoff at DELTA halves the atomic count.
__global__ __launch_bounds__(256)
void scatter25_kernel(const float* __restrict__ coords,
                      const int* __restrict__ num_atoms,
                      float* __restrict__ out) {
    int idx = blockIdx.x * blockDim.x + threadIdx.x;
    const int total = BT * MAXA * 25;
    if (idx >= total) return;

    int r  = idx % 25;            // (dx, dy) pair
    int t  = idx / 25;
    int a  = t % MAXA;
    int bt = t / MAXA;
    if (a >= num_atoms[bt]) return;

    const float* p = coords + (size_t)bt * (3 * MAXA) + (size_t)a * 3;
    float px = p[0], py = p[1], pz = p[2];

    int dy = r % 5;
    int dx = r / 5;
    int nx = (int)floorf(px) + dx - NNB;
    int ny = (int)floorf(py) + dy - NNB;
    if ((unsigned)nx >= BOX || (unsigned)ny >= BOX) return;

    float fx = (float)nx - px;
    float fy = (float)ny - py;
    float exy = __expf(-(fx * fx + fy * fy));
    if (exy < DELTA) return;      // exp(-fz^2) <= 1, so whole row is negligible

    int cz = (int)floorf(pz);
    float* row = out + (size_t)bt * BOX3 + (size_t)(nx * BOX + ny) * BOX;
    #pragma unroll
    for (int dz = 0; dz < 5; ++dz) {
        int nz = cz + dz - NNB;
        if ((unsigned)nz >= BOX) continue;
        float fz = (float)nz - pz;
        float v = exy * __expf(-fz * fz);
        if (v >= DELTA) atomicAdd(row + nz, v);
    }
}

extern "C" void kernel_launch(void* const* d_in, const int* in_sizes, int n_in,
                              void* d_out, int out_size, void* d_ws, size_t ws_size,
                              hipStream_t stream) {
    const float* coords    = (const float*)d_in[0];   // [4, 11, 1536] fp32
    const int*   num_atoms = (const int*)d_in[1];     // [4, 11] int32
    float*       out       = (float*)d_out;           // [4, 11, 120^3] fp32

    // 1) zero the 304 MB output (harness poisons it with 0xAA)
    int n4 = out_size / 4;                            // 19,008,000 float4s
    {
        int threads = (n4 + 1) / 2;
        const int block = 256;
        zero_out_kernel<<<(threads + block - 1) / block, block, 0, stream>>>(
            (float4*)d_out, n4);
    }

    // 2) sparse Gaussian scatter
    {
        const int total = BT * MAXA * 25;             // 563,200
        const int block = 256;
        scatter25_kernel<<<(total + block - 1) / block, block, 0, stream>>>(
            coords, num_atoms, out);
    }
}

// Round 6
// 330.335 us; speedup vs baseline: 1.0734x; 1.0419x over previous
//
#include <hip/hip_runtime.h>
#include <stdint.h>

// Problem constants (from reference)
#define BOX 120
#define BOX2 (BOX * BOX)            // 14400
#define BOX3 (BOX * BOX * BOX)      // 1,728,000
#define NTYPES 11
#define NBATCH 4
#define BT (NBATCH * NTYPES)        // 44
#define MAXA 512
#define NNB 2

// Contribution cutoff: atoms whose exp(-fx^2) < DELTA are dropped (their max
// voxel contribution is < DELTA since the y/z factors are <= 1). Validated in
// R4: absmax 3.9e-3 vs 3.36e-2 threshold.
#define DELTA 2e-3f

// x-column binning: bins[(bt,cx)] holds atom indices with floor(px)==cx.
// lambda <= 512/120 = 4.27 atoms/bin -> P(count > 24) ~ 5e-12.
#define BINCAP 24
#define NBINS (BT * BOX)                              // 5280
#define SLOTS (5 * BINCAP)                            // 120 candidate slots
#define WS_COUNTS_BYTES ((size_t)NBINS * 4)           // 21,120
#define WS_BINS_BYTES   ((size_t)NBINS * BINCAP * 2)  // 253,440
#define WS_NEEDED       (WS_COUNTS_BYTES + WS_BINS_BYTES)

typedef float v4f __attribute__((ext_vector_type(4)));  // native vector for nontemporal store

__global__ __launch_bounds__(256)
void zero_counts_kernel(uint32_t* __restrict__ counts) {
    int i = blockIdx.x * blockDim.x + threadIdx.x;
    if (i < NBINS) counts[i] = 0u;
}

__global__ __launch_bounds__(256)
void bin_kernel(const float* __restrict__ coords,
                const int* __restrict__ num_atoms,
                uint32_t* __restrict__ counts,
                uint16_t* __restrict__ bins) {
    int tid = blockIdx.x * blockDim.x + threadIdx.x;
    if (tid >= BT * MAXA) return;
    int bt = tid / MAXA;
    int a  = tid % MAXA;
    if (a >= num_atoms[bt]) return;
    float px = coords[(size_t)bt * (3 * MAXA) + 3 * (size_t)a];
    int cx = (int)floorf(px);
    if ((unsigned)cx >= BOX) return;                  // margin=5 -> never taken
    int bin = bt * BOX + cx;
    uint32_t k = atomicAdd(&counts[bin], 1u);
    if (k < BINCAP) bins[(size_t)bin * BINCAP + k] = (uint16_t)a;
}

// One block per (bt, x) slab: produces 120*120 voxels = 3600 float4s,
// write-only, no atomics, no pre-zero pass. Candidate atoms live in x-columns
// [x-2, x+2] (exact cell-based x-window, matching the reference's
// neighbour-cell truncation). y/z truncation is the exact cell window
// |voxel - floor(pos)| <= 2 per axis.
__global__ __launch_bounds__(256)
void gather_slab_kernel(const float* __restrict__ coords,
                        const uint32_t* __restrict__ counts,
                        const uint16_t* __restrict__ bins,
                        v4f* __restrict__ out4) {
    int b  = blockIdx.x;
    int bt = b / BOX;
    int x  = b % BOX;

    __shared__ float4 s_at[SLOTS];   // (py, pz, floor(py), floor(pz))
    __shared__ float  s_ex[SLOTS];   // exp(-(x-px)^2)
    __shared__ int    s_n;
    if (threadIdx.x == 0) s_n = 0;
    __syncthreads();

    int t = threadIdx.x;
    if (t < SLOTS) {
        int cx = x - NNB + t / BINCAP;
        int k  = t % BINCAP;
        if ((unsigned)cx < BOX) {
            int bin = bt * BOX + cx;
            uint32_t c = counts[bin];
            if (c > BINCAP) c = BINCAP;
            if ((uint32_t)k < c) {
                int a = bins[(size_t)bin * BINCAP + k];
                const float* p = coords + (size_t)bt * (3 * MAXA) + 3 * (size_t)a;
                float px = p[0], py = p[1], pz = p[2];
                float fx = (float)x - px;
                float ex = __expf(-fx * fx);
                if (ex >= DELTA) {
                    int i = atomicAdd(&s_n, 1);
                    s_at[i] = make_float4(py, pz, floorf(py), floorf(pz));
                    s_ex[i] = ex;
                }
            }
        }
    }
    __syncthreads();
    int n = s_n;

    size_t obase = (size_t)b * (BOX2 / 4);            // 3600 float4 per slab
    // 3600 float4s, 256 threads, 15 strided chunks; consecutive lanes write
    // consecutive float4s -> 1 KB fully-coalesced per wave store.
    for (int i = 0; i < 15; ++i) {
        int v4 = threadIdx.x + (i << 8);
        if (v4 < BOX2 / 4) {
            int y  = v4 / (BOX / 4);                  // 30 float4 per y-row
            int z0 = (v4 % (BOX / 4)) * 4;
            float yf = (float)y;
            float a0 = 0.f, a1 = 0.f, a2 = 0.f, a3 = 0.f;
            for (int j = 0; j < n; ++j) {
                float4 at = s_at[j];                  // LDS broadcast (same addr all lanes)
                if (fabsf(yf - at.z) <= 2.0f) {       // exact y cell window
                    float dy  = yf - at.x;
                    float exy = s_ex[j] * __expf(-dy * dy);
                    if (exy >= DELTA) {
                        float pz = at.y, fpz = at.w;
                        float zf = (float)z0;
                        float dz0 = zf - pz, dz1 = zf + 1.f - pz,
                              dz2 = zf + 2.f - pz, dz3 = zf + 3.f - pz;
                        if (fabsf(zf - fpz)        <= 2.0f) a0 += exy * __expf(-dz0 * dz0);
                        if (fabsf(zf + 1.f - fpz)  <= 2.0f) a1 += exy * __expf(-dz1 * dz1);
                        if (fabsf(zf + 2.f - fpz)  <= 2.0f) a2 += exy * __expf(-dz2 * dz2);
                        if (fabsf(zf + 3.f - fpz)  <= 2.0f) a3 += exy * __expf(-dz3 * dz3);
                    }
                }
            }
            v4f acc = { a0, a1, a2, a3 };
            __builtin_nontemporal_store(acc, out4 + obase + v4);
        }
    }
}

// ---------------- fallback (R2 structure) if ws is too small ----------------

__global__ __launch_bounds__(256)
void zero_out_kernel(float4* __restrict__ out, int n4) {
    int i = blockIdx.x * blockDim.x + threadIdx.x;
    if (i < n4) out[i] = make_float4(0.f, 0.f, 0.f, 0.f);
}

__global__ __launch_bounds__(256)
void scatter_kernel(const float* __restrict__ coords,
                    const int* __restrict__ num_atoms,
                    float* __restrict__ out) {
    int idx = blockIdx.x * blockDim.x + threadIdx.x;
    const int total = BT * MAXA * 125;
    if (idx >= total) return;
    int k   = idx % 125;
    int tmp = idx / 125;
    int a   = tmp % MAXA;
    int bt  = tmp / MAXA;
    if (a >= num_atoms[bt]) return;
    const float* p = coords + (size_t)bt * (3 * MAXA) + 3 * (size_t)a;
    float px = p[0], py = p[1], pz = p[2];
    int dz = k % 5, t2 = k / 5;
    int dy = t2 % 5, dx = t2 / 5;
    int nx = (int)floorf(px) + dx - NNB;
    int ny = (int)floorf(py) + dy - NNB;
    int nz = (int)floorf(pz) + dz - NNB;
    if ((unsigned)nx >= BOX || (unsigned)ny >= BOX || (unsigned)nz >= BOX) return;
    float fx = (float)nx - px, fy = (float)ny - py, fz = (float)nz - pz;
    float val = __expf(-(fx * fx + fy * fy + fz * fz));
    atomicAdd(out + (size_t)bt * BOX3 + (size_t)((nx * BOX + ny) * BOX + nz), val);
}

extern "C" void kernel_launch(void* const* d_in, const int* in_sizes, int n_in,
                              void* d_out, int out_size, void* d_ws, size_t ws_size,
                              hipStream_t stream) {
    const float* coords    = (const float*)d_in[0];   // [4, 11, 1536] fp32
    const int*   num_atoms = (const int*)d_in[1];     // [4, 11] int32

    if (ws_size >= WS_NEEDED) {
        uint32_t* counts = (uint32_t*)d_ws;
        uint16_t* bins   = (uint16_t*)((char*)d_ws + WS_COUNTS_BYTES);

        zero_counts_kernel<<<(NBINS + 255) / 256, 256, 0, stream>>>(counts);
        bin_kernel<<<(BT * MAXA + 255) / 256, 256, 0, stream>>>(
            coords, num_atoms, counts, bins);
        gather_slab_kernel<<<NBINS, 256, 0, stream>>>(
            coords, counts, bins, (v4f*)d_out);
    } else {
        int n4 = out_size / 4;
        zero_out_kernel<<<(n4 + 255) / 256, 256, 0, stream>>>((float4*)d_out, n4);
        const int total = BT * MAXA * 125;
        scatter_kernel<<<(total + 255) / 256, 256, 0, stream>>>(
            coords, num_atoms, (float*)d_out);
    }
}